// Round 5
// baseline (573.226 us; speedup 1.0000x reference)
//
#include <hip/hip_runtime.h>
#include <hip/hip_fp16.h>

#define NB 64
#define TT 1024
#define FF 256
#define HH 256
#define GG 768
#define AA 8
#define KP 288          // padded K: 256 (x) + 8 (a) + 24 zeros
#define MM (NB*TT)      // 65536 rows
#define SGRP 16         // sequences batched per scan unit (MFMA M=16)
#define WCH 8           // time-window per chunk
#define NCH (TT/WCH)    // 128 chunks
#define LDH 264         // LDS row stride (halfs) for h16/rh16
#define GSP 776         // LDS row stride (halfs) for staged gxa rows (768+8)

typedef _Float16 h2v __attribute__((ext_vector_type(2)));
typedef _Float16 v8h __attribute__((ext_vector_type(8)));
typedef float    v4f __attribute__((ext_vector_type(4)));

static __device__ __forceinline__ unsigned pk_rtn(float a, float b) {
    unsigned lo = (unsigned)__half_as_ushort(__float2half(a));
    unsigned hi = (unsigned)__half_as_ushort(__float2half(b));
    return lo | (hi << 16);
}
static __device__ __forceinline__ float h2f(unsigned short u) {
    return (float)__builtin_bit_cast(_Float16, u);
}
static __device__ __forceinline__ unsigned short f2h(float f) {
    return __half_as_ushort(__float2half(f));
}

// ---------------------------------------------------------------------------
// Kernel 0: reset-dtype detection + canonicalization to uint8, PLUS the
// first-reset table Ftab[n*(NCH+1)+c] = first t >= c*WCH with reset[n][t]
// (else TT). Single block.
// ---------------------------------------------------------------------------
__global__ __launch_bounds__(1024) void fix_reset(
    const unsigned* __restrict__ src, unsigned char* __restrict__ dst,
    int* __restrict__ Ftab)
{
    __shared__ unsigned red[16];
    const int tid = threadIdx.x;

    unsigned acc = 0;
    #pragma unroll
    for (int i = 0; i < 16; i++)
        acc |= src[tid * 16 + i] & 0xFFFFFF00u;
    #pragma unroll
    for (int off = 32; off >= 1; off >>= 1)
        acc |= __shfl_down(acc, off, 64);
    if ((tid & 63) == 0) red[tid >> 6] = acc;
    __syncthreads();
    unsigned flag = 0;
    #pragma unroll
    for (int i = 0; i < 16; i++) flag |= red[i];
    const bool is_i32 = (flag == 0);

    if (is_i32) {
        const int per = (NB * TT) / 1024;   // 64
        #pragma unroll
        for (int i = 0; i < per; i++) {
            int idx = tid * per + i;
            dst[idx] = (unsigned char)(src[idx] != 0 ? 1 : 0);
        }
    } else {
        unsigned* d4 = (unsigned*)dst;
        #pragma unroll
        for (int i = 0; i < 16; i++)
            d4[tid * 16 + i] = src[tid * 16 + i];
    }
    __syncthreads();   // rst8 fully written & drained before Ftab scan

    for (int v = tid; v < NB * (NCH + 1); v += 1024) {
        int n = v / (NCH + 1), c = v - n * (NCH + 1);
        int s = TT;
        const unsigned char* r = dst + n * TT;
        for (int t = c * WCH; t < TT; t++)
            if (r[t]) { s = t; break; }
        Ftab[v] = s;
    }
}

// ---------------------------------------------------------------------------
// Kernel 1: merged weight prep (unchanged).
// ---------------------------------------------------------------------------
__global__ __launch_bounds__(256) void prep_weights(
    const float* __restrict__ w_i, const float* __restrict__ w_a,
    const float* __restrict__ w_h, const float* __restrict__ ihg,
    float* __restrict__ out3,
    unsigned short* __restrict__ wt, unsigned* __restrict__ whb)
{
    const int bid = blockIdx.x;
    if (bid < 865) {
        int idx = bid * 256 + threadIdx.x;
        const int E2 = GG * KP;          // 221,184
        if (idx < E2) {
            int g = idx / KP, k = idx - g * KP;
            float v = 0.f;
            if (k < FF)            v = w_i[k * GG + g];
            else if (k < FF + AA)  v = w_a[(k - FF) * GG + g];
            wt[idx] = f2h(v);
        } else if (idx < E2 + HH) {
            int i = idx - E2;
            out3[i] = ihg[i];
        }
    } else {
        int j = (bid - 865) * 256 + threadIdx.x;   // dword index, 0..98303
        int w    = j / 12288;
        int r    = j - w * 12288;
        int tile = r >> 8;
        int r2   = r & 255;
        int lane = r2 >> 2, d = r2 & 3;
        int r15 = lane & 15, q = lane >> 4;
        int g, k;
        if (tile < 32) {
            int nt = tile >> 3, kt = tile & 7;
            g = (nt < 2) ? (w * 32 + nt * 16 + r15)
                         : (256 + w * 32 + (nt - 2) * 16 + r15);
            k = kt * 32 + q * 8 + 2 * d;
        } else {
            int t2 = tile - 32;
            int nt2 = t2 >> 3, kt = t2 & 7;
            g = 512 + w * 32 + nt2 * 16 + r15;
            k = kt * 32 + q * 8 + 2 * d;
        }
        whb[j] = pk_rtn(w_h[k * GG + g], w_h[(k + 1) * GG + g]);
    }
}

// ---------------------------------------------------------------------------
// Kernel 2: gxa[MM][GG] (fp16) = [x|a|0] @ W + bias (unchanged).
// ---------------------------------------------------------------------------
#define LDK 40

__global__ __launch_bounds__(256, 3) void gemm_fused(
    const float* __restrict__ x, const float* __restrict__ a,
    const unsigned short* __restrict__ wt,
    const float* __restrict__ bias, unsigned short* __restrict__ gxa)
{
    __shared__ __align__(16) unsigned short As[2][128 * LDK];
    __shared__ __align__(16) unsigned short Bs[2][128 * LDK];

    const int bid = blockIdx.x;
    const int wg  = (bid & 7) * 384 + (bid >> 3);   // bijective XCD swizzle
    const int gt = wg % 6, mt = wg / 6;
    const int tid = threadIdx.x;
    const int lane = tid & 63, wv = tid >> 6;
    const int srow = tid & 127, shf = tid >> 7;
    const int r15 = lane & 15, q = lane >> 4;

    v4f acc[2][8];
    #pragma unroll
    for (int i = 0; i < 2; i++)
        #pragma unroll
        for (int j = 0; j < 8; j++) acc[i][j] = (v4f){0.f, 0.f, 0.f, 0.f};

    const int arow = mt * 128 + srow;
    const int brow = gt * 128 + srow;

    float4 f0, f1, f2, f3;
    uint4  pb0, pb1;

    auto issue = [&](int kc) {
        if (kc < 8) {
            const float4* sp = (const float4*)(x + (size_t)arow * FF + kc * 32 + shf * 16);
            f0 = sp[0]; f1 = sp[1]; f2 = sp[2]; f3 = sp[3];
        } else if (shf == 0) {
            const float4* ap = (const float4*)(a + (size_t)arow * AA);
            f0 = ap[0]; f1 = ap[1];
        }
        const uint4* srcB = (const uint4*)(wt + brow * KP + kc * 32 + shf * 16);
        pb0 = srcB[0]; pb1 = srcB[1];
    };
    auto commit = [&](int buf, int kc) {
        uint4 A0, A1;
        if (kc < 8) {
            A0.x = pk_rtn(f0.x, f0.y); A0.y = pk_rtn(f0.z, f0.w);
            A0.z = pk_rtn(f1.x, f1.y); A0.w = pk_rtn(f1.z, f1.w);
            A1.x = pk_rtn(f2.x, f2.y); A1.y = pk_rtn(f2.z, f2.w);
            A1.z = pk_rtn(f3.x, f3.y); A1.w = pk_rtn(f3.z, f3.w);
        } else {
            if (shf == 0) {
                A0.x = pk_rtn(f0.x, f0.y); A0.y = pk_rtn(f0.z, f0.w);
                A0.z = pk_rtn(f1.x, f1.y); A0.w = pk_rtn(f1.z, f1.w);
            } else {
                A0 = (uint4){0, 0, 0, 0};
            }
            A1 = (uint4){0, 0, 0, 0};
        }
        *(uint4*)(As[buf] + srow * LDK + shf * 16)     = A0;
        *(uint4*)(As[buf] + srow * LDK + shf * 16 + 8) = A1;
        *(uint4*)(Bs[buf] + srow * LDK + shf * 16)     = pb0;
        *(uint4*)(Bs[buf] + srow * LDK + shf * 16 + 8) = pb1;
    };

    issue(0);
    commit(0, 0);
    __syncthreads();

    for (int kc = 0; kc < 9; kc++) {
        const int cur = kc & 1;
        if (kc < 8) issue(kc + 1);

        v8h af[2], bf[8];
        #pragma unroll
        for (int mi = 0; mi < 2; mi++)
            af[mi] = *(const v8h*)(As[cur] + (wv * 32 + mi * 16 + r15) * LDK + q * 8);
        #pragma unroll
        for (int nj = 0; nj < 8; nj++)
            bf[nj] = *(const v8h*)(Bs[cur] + (nj * 16 + r15) * LDK + q * 8);
        #pragma unroll
        for (int mi = 0; mi < 2; mi++)
            #pragma unroll
            for (int nj = 0; nj < 8; nj++)
                acc[mi][nj] = __builtin_amdgcn_mfma_f32_16x16x32_f16(
                    af[mi], bf[nj], acc[mi][nj], 0, 0, 0);

        if (kc < 8) {
            commit(cur ^ 1, kc + 1);
            __syncthreads();
        }
    }

    #pragma unroll
    for (int mi = 0; mi < 2; mi++) {
        #pragma unroll
        for (int nj = 0; nj < 8; nj++) {
            int col = gt * 128 + nj * 16 + r15;
            float bv = bias[col];
            #pragma unroll
            for (int v = 0; v < 4; v++) {
                int row = mt * 128 + wv * 32 + mi * 16 + q * 4 + v;
                float val = acc[mi][nj][v] + bv;
                gxa[row * GG + col] = f2h(val);
            }
        }
    }
}

// ---------------------------------------------------------------------------
// Kernel 3: dual-window MFMA GRU scan. Each block (512 thr, 8 waves) now
// runs TWO independent 16-seq x 8-step window-units (chunks c0 and c0+64),
// sharing the weight registers, waL LDS tiles and the 2 barriers. 32 output
// rows per block -> window shrinks 16->8, serial steps ~22->~15, and the
// second unit's independent MFMA/VALU chains fill the latency bubbles
// (round-4 counters: MfmaUtil 10%, VALUBusy 32% -> stall-bound).
// gxa staging: single-buffered per unit with split commit points (a-part at
// step top, zr-part before B2) — race-free under the existing 2 barriers;
// t+1 loads issued right after B1 so they only drain at B2 (~1000cy later).
// ---------------------------------------------------------------------------
__global__ __launch_bounds__(512, 2) void scan_mfma(
    const unsigned short* __restrict__ gxa, const uint4* __restrict__ whb4,
    const unsigned char* __restrict__ rst, const int* __restrict__ Ftab,
    const float* __restrict__ ihg, float* __restrict__ out)
{
    __shared__ __align__(16) unsigned short h16[2][SGRP * LDH];
    __shared__ __align__(16) unsigned short rh16[2][SGRP * LDH];
    __shared__ __align__(16) unsigned short gs[2][SGRP * GSP];
    __shared__ __align__(16) uint4 waL[8 * 8 * 64];   // aa1 tiles [w][kt][lane]
    __shared__ int s_len[2];

    const int tid = threadIdx.x;
    const int w = tid >> 6, lane = tid & 63;
    const int r15 = lane & 15, q = lane >> 4;
    const int grp = blockIdx.x >> 6;        // 0..3
    const int c0  = blockIdx.x & 63;        // unit A chunk; unit B = c0+64
    const int n0  = grp * SGRP;
    const int S0  = c0 * WCH, S1 = (c0 + 64) * WCH;

    // ---- weights: 40 reg fragments + 8 LDS fragments per wave (shared) ----
    uint4 wb[40];
    #pragma unroll
    for (int i = 0; i < 40; i++) wb[i] = whb4[(w * 48 + i) * 64 + lane];
    #pragma unroll
    for (int rr = 0; rr < 8; rr++)
        waL[rr * 512 + tid] = whb4[(rr * 48 + 40 + (tid >> 6)) * 64 + (tid & 63)];

    // ---- per-unit lengths (block-uniform): max te over 16 seqs ----
    if (tid < 32) {
        int uu = tid >> 4, sq = tid & 15;
        int cc = c0 + (uu ? 64 : 0);
        int te = Ftab[(n0 + sq) * (NCH + 1) + cc + 1];
        #pragma unroll
        for (int off = 8; off >= 1; off >>= 1)
            te = max(te, __shfl_xor(te, off, 64));
        if (sq == 0) s_len[uu] = te - (uu ? S1 : S0);
    }

    // ---- init h16 for both units ----
    for (int idx = tid; idx < 2 * SGRP * HH; idx += 512) {
        int u = idx >> 12, r = idx & 4095;
        int sq = r >> 8, jj = r & 255;
        int Su = u ? S1 : S0;
        bool rb = (Su == 0) || (rst[(n0 + sq) * TT + Su] != 0);
        h16[u][sq * LDH + jj] = f2h(rb ? ihg[jj] : 0.f);
    }

    const int j0 = w * 32 + r15, j1 = j0 + 16;
    const float ih0 = ihg[j0], ih1 = ihg[j1];

    int   seqi[4];
    int   tbte[2][4];
    float hcr[2][8];
    #pragma unroll
    for (int v = 0; v < 4; v++) {
        int sq = q * 4 + v;
        seqi[v] = (n0 + sq) * TT;
        #pragma unroll
        for (int u = 0; u < 2; u++) {
            int cc = c0 + (u ? 64 : 0);
            int Su = u ? S1 : S0;
            int tb = (cc == 0) ? 0 : Ftab[(n0 + sq) * (NCH + 1) + cc];
            int te = Ftab[(n0 + sq) * (NCH + 1) + cc + 1];
            tbte[u][v] = tb | (te << 16);
            bool rb = (Su == 0) || (rst[seqi[v] + Su] != 0);
            hcr[u][v]     = rb ? ih0 : 0.f;
            hcr[u][4 + v] = rb ? ih1 : 0.f;
        }
    }

    // ---- prologue staging: load zr(S)+a(S); commit zr now, hold a ----
    const int seqS = tid >> 5, jS = tid & 31;
    uint4 aReg[2];
    #pragma unroll
    for (int u = 0; u < 2; u++) {
        int Su = u ? S1 : S0;
        const uint4* sp = (const uint4*)(gxa + ((size_t)((n0 + seqS) * TT + Su)) * GG);
        uint4 z0 = sp[jS], z1 = sp[jS + 32];
        aReg[u] = sp[jS + 64];
        uint4* dp = (uint4*)(gs[u] + seqS * GSP);
        dp[jS] = z0; dp[jS + 32] = z1;
    }
    __syncthreads();

    const int L = max(s_len[0], s_len[1]);
    const v4f z4 = {0.f, 0.f, 0.f, 0.f};
    uint4 zrN0[2], zrN1[2];

    for (int s = 0; s < L; s++) {
        // ---- commit a(t) (loaded last iter / prologue); read in epi2 after B1
        #pragma unroll
        for (int u = 0; u < 2; u++)
            ((uint4*)(gs[u] + seqS * GSP))[64 + jS] = aReg[u];

        // ---- phase 1: zr = h @ Wzr, both units (64 MFMAs/wave) ----
        v4f az0[2], az1[2], ar0[2], ar1[2];
        #pragma unroll
        for (int u = 0; u < 2; u++) { az0[u]=z4; az1[u]=z4; ar0[u]=z4; ar1[u]=z4; }
        #pragma unroll
        for (int kt = 0; kt < 8; kt++) {
            v8h afA = *(const v8h*)(h16[0] + r15 * LDH + kt * 32 + q * 8);
            v8h afB = *(const v8h*)(h16[1] + r15 * LDH + kt * 32 + q * 8);
            az0[0] = __builtin_amdgcn_mfma_f32_16x16x32_f16(afA, __builtin_bit_cast(v8h, wb[kt]),      az0[0], 0, 0, 0);
            az0[1] = __builtin_amdgcn_mfma_f32_16x16x32_f16(afB, __builtin_bit_cast(v8h, wb[kt]),      az0[1], 0, 0, 0);
            az1[0] = __builtin_amdgcn_mfma_f32_16x16x32_f16(afA, __builtin_bit_cast(v8h, wb[8 + kt]),  az1[0], 0, 0, 0);
            az1[1] = __builtin_amdgcn_mfma_f32_16x16x32_f16(afB, __builtin_bit_cast(v8h, wb[8 + kt]),  az1[1], 0, 0, 0);
            ar0[0] = __builtin_amdgcn_mfma_f32_16x16x32_f16(afA, __builtin_bit_cast(v8h, wb[16 + kt]), ar0[0], 0, 0, 0);
            ar0[1] = __builtin_amdgcn_mfma_f32_16x16x32_f16(afB, __builtin_bit_cast(v8h, wb[16 + kt]), ar0[1], 0, 0, 0);
            ar1[0] = __builtin_amdgcn_mfma_f32_16x16x32_f16(afA, __builtin_bit_cast(v8h, wb[24 + kt]), ar1[0], 0, 0, 0);
            ar1[1] = __builtin_amdgcn_mfma_f32_16x16x32_f16(afB, __builtin_bit_cast(v8h, wb[24 + kt]), ar1[1], 0, 0, 0);
        }

        // ---- epi 1: sigmoid; z local; rh -> LDS ----
        float zs[2][8];
        #pragma unroll
        for (int u = 0; u < 2; u++) {
            const unsigned short* g = gs[u];
            #pragma unroll
            for (int v = 0; v < 4; v++) {
                int sq = q * 4 + v, gb = sq * GSP;
                float z0 = az0[u][v] + h2f(g[gb + j0]);
                float z1 = az1[u][v] + h2f(g[gb + j1]);
                zs[u][v]     = 1.f / (1.f + __expf(-z0));
                zs[u][4 + v] = 1.f / (1.f + __expf(-z1));
                float r0 = ar0[u][v] + h2f(g[gb + 256 + j0]);
                float r1 = ar1[u][v] + h2f(g[gb + 256 + j1]);
                float sg0 = 1.f / (1.f + __expf(-r0));
                float sg1 = 1.f / (1.f + __expf(-r1));
                rh16[u][sq * LDH + j0] = f2h(sg0 * hcr[u][v]);
                rh16[u][sq * LDH + j1] = f2h(sg1 * hcr[u][4 + v]);
            }
        }
        __syncthreads();   // B1

        // ---- issue t+1 loads; only vmcnt-drain they meet is B2 (~1000cy) ----
        unsigned char rn[2][4];
        #pragma unroll
        for (int u = 0; u < 2; u++) {
            int trd = min((u ? S1 : S0) + s + 1, TT - 1);
            const uint4* sp = (const uint4*)(gxa + ((size_t)((n0 + seqS) * TT + trd)) * GG);
            zrN0[u] = sp[jS]; zrN1[u] = sp[jS + 32]; aReg[u] = sp[jS + 64];
            #pragma unroll
            for (int v = 0; v < 4; v++)
                rn[u][v] = rst[seqi[v] + trd];
        }

        // ---- phase 2: a = rh @ Wa, both units (32 MFMAs/wave) ----
        v4f aa0[2], aa1[2];
        #pragma unroll
        for (int u = 0; u < 2; u++) { aa0[u]=z4; aa1[u]=z4; }
        #pragma unroll
        for (int kt = 0; kt < 8; kt++) {
            uint4 wv4 = waL[(w * 8 + kt) * 64 + lane];
            v8h pfA = *(const v8h*)(rh16[0] + r15 * LDH + kt * 32 + q * 8);
            v8h pfB = *(const v8h*)(rh16[1] + r15 * LDH + kt * 32 + q * 8);
            aa0[0] = __builtin_amdgcn_mfma_f32_16x16x32_f16(pfA, __builtin_bit_cast(v8h, wb[32 + kt]), aa0[0], 0, 0, 0);
            aa0[1] = __builtin_amdgcn_mfma_f32_16x16x32_f16(pfB, __builtin_bit_cast(v8h, wb[32 + kt]), aa0[1], 0, 0, 0);
            aa1[0] = __builtin_amdgcn_mfma_f32_16x16x32_f16(pfA, __builtin_bit_cast(v8h, wv4),         aa1[0], 0, 0, 0);
            aa1[1] = __builtin_amdgcn_mfma_f32_16x16x32_f16(pfB, __builtin_bit_cast(v8h, wv4),         aa1[1], 0, 0, 0);
        }

        // ---- epi 2: tanh, state update, masked stores, next reset ----
        #pragma unroll
        for (int u = 0; u < 2; u++) {
            const unsigned short* g = gs[u];
            const int t = (u ? S1 : S0) + s;
            #pragma unroll
            for (int v = 0; v < 4; v++) {
                int sq = q * 4 + v, gb = sq * GSP;
                int tb = tbte[u][v] & 0xFFFF, te = tbte[u][v] >> 16;
                bool wr = (t >= tb) && (t < te);
                int mo = (seqi[v] + t) * HH;
                float u0 = aa0[u][v] + h2f(g[gb + 512 + j0]);
                float u1 = aa1[u][v] + h2f(g[gb + 512 + j1]);
                float e0 = __expf(2.f * u0), e1 = __expf(2.f * u1);
                float t0 = (e0 - 1.f) / (e0 + 1.f);
                float t1 = (e1 - 1.f) / (e1 + 1.f);
                float hn0 = hcr[u][v]     + zs[u][v]     * (t0 - hcr[u][v]);
                float hn1 = hcr[u][4 + v] + zs[u][4 + v] * (t1 - hcr[u][4 + v]);
                if (wr) {
                    out[mo + j0] = hn0;
                    out[mo + j1] = hn1;
                    out[MM * HH + mo + j0] = hn0;
                    out[MM * HH + mo + j1] = hn1;
                }
                bool rb = rn[u][v] != 0;
                float g0f = rb ? ih0 : hn0;
                float g1f = rb ? ih1 : hn1;
                hcr[u][v] = g0f; hcr[u][4 + v] = g1f;
                h16[u][sq * LDH + j0] = f2h(g0f);
                h16[u][sq * LDH + j1] = f2h(g1f);
            }
        }

        // ---- commit zr(t+1) (readers resume after B2) ----
        #pragma unroll
        for (int u = 0; u < 2; u++) {
            uint4* dp = (uint4*)(gs[u] + seqS * GSP);
            dp[jS] = zrN0[u]; dp[jS + 32] = zrN1[u];
        }
        __syncthreads();   // B2
    }
}

// ---------------------------------------------------------------------------
extern "C" void kernel_launch(void* const* d_in, const int* in_sizes, int n_in,
                              void* d_out, int out_size, void* d_ws, size_t ws_size,
                              hipStream_t stream)
{
    const float* x   = (const float*)d_in[0];
    const float* a   = (const float*)d_in[1];
    const void*  rsv = d_in[2];
    const float* w_i = (const float*)d_in[3];
    const float* w_h = (const float*)d_in[4];
    const float* w_a = (const float*)d_in[5];
    const float* b   = (const float*)d_in[6];
    const float* ih  = (const float*)d_in[7];
    float*       out = (float*)d_out;

    char* ws = (char*)d_ws;
    size_t o = 0;
    unsigned short* gxa  = (unsigned short*)(ws + o); o += (size_t)MM * GG * 2;  // 96 MB
    unsigned short* wt   = (unsigned short*)(ws + o); o += (size_t)GG * KP * 2;  // 0.44 MB
    unsigned char*  rst8 = (unsigned char*) (ws + o); o += (size_t)NB * TT;      // 64 KB
    unsigned*       whb  = (unsigned*)      (ws + o); o += 98304u * 4;           // 384 KB
    int*            Ftab = (int*)           (ws + o);                            // 64*129 ints (33 KB)

    fix_reset<<<1, 1024, 0, stream>>>((const unsigned*)rsv, rst8, Ftab);

    prep_weights<<<865 + 384, 256, 0, stream>>>(
        w_i, w_a, w_h, ih, out + (size_t)2 * MM * HH, wt, whb);

    gemm_fused<<<512 * 6, 256, 0, stream>>>(x, a, wt, b, gxa);

    scan_mfma<<<(NB / SGRP) * 64, 512, 0, stream>>>(
        gxa, (const uint4*)whb, rst8, Ftab, ih, out);
}

// Round 6
// 387.615 us; speedup vs baseline: 1.4789x; 1.4789x over previous
//
#include <hip/hip_runtime.h>
#include <hip/hip_fp16.h>

#define NB 64
#define TT 1024
#define FF 256
#define HH 256
#define GG 768
#define AA 8
#define KP 288          // padded K: 256 (x) + 8 (a) + 24 zeros
#define MM (NB*TT)      // 65536 rows
#define SGRP 16         // sequences batched per scan block (MFMA M=16)
#define WCH 16          // time-window per chunk
#define NCH (TT/WCH)    // 64 chunks
#define LDH 264         // LDS row stride (halfs) for h16/rh16
#define GSP 776         // LDS row stride (halfs) for staged gxa rows (768+8)

typedef _Float16 h2v __attribute__((ext_vector_type(2)));
typedef _Float16 v8h __attribute__((ext_vector_type(8)));
typedef float    v4f __attribute__((ext_vector_type(4)));

static __device__ __forceinline__ unsigned pk_rtn(float a, float b) {
    unsigned lo = (unsigned)__half_as_ushort(__float2half(a));
    unsigned hi = (unsigned)__half_as_ushort(__float2half(b));
    return lo | (hi << 16);
}
static __device__ __forceinline__ float h2f(unsigned short u) {
    return (float)__builtin_bit_cast(_Float16, u);
}
static __device__ __forceinline__ unsigned short f2h(float f) {
    return __half_as_ushort(__float2half(f));
}

// LDS-only barrier: waits LDS ops but does NOT drain vmcnt, so global
// prefetch loads and output stores stay in flight across it. All inter-wave
// communication in scan_mfma is through LDS, so this is sufficient.
// sched_barrier(0) pins ordering (guide rule #18).
static __device__ __forceinline__ void bar_lds() {
    __builtin_amdgcn_sched_barrier(0);
    asm volatile("s_waitcnt lgkmcnt(0)" ::: "memory");
    __builtin_amdgcn_sched_barrier(0);
    __builtin_amdgcn_s_barrier();
    __builtin_amdgcn_sched_barrier(0);
}

// ---------------------------------------------------------------------------
// Kernel 0: reset-dtype detection + canonicalization to uint8, PLUS the
// first-reset table Ftab[n*(NCH+1)+c] = first t >= c*WCH with reset[n][t]
// (else TT). Single block.
// ---------------------------------------------------------------------------
__global__ __launch_bounds__(1024) void fix_reset(
    const unsigned* __restrict__ src, unsigned char* __restrict__ dst,
    int* __restrict__ Ftab)
{
    __shared__ unsigned red[16];
    const int tid = threadIdx.x;

    unsigned acc = 0;
    #pragma unroll
    for (int i = 0; i < 16; i++)
        acc |= src[tid * 16 + i] & 0xFFFFFF00u;
    #pragma unroll
    for (int off = 32; off >= 1; off >>= 1)
        acc |= __shfl_down(acc, off, 64);
    if ((tid & 63) == 0) red[tid >> 6] = acc;
    __syncthreads();
    unsigned flag = 0;
    #pragma unroll
    for (int i = 0; i < 16; i++) flag |= red[i];
    const bool is_i32 = (flag == 0);

    if (is_i32) {
        const int per = (NB * TT) / 1024;   // 64
        #pragma unroll
        for (int i = 0; i < per; i++) {
            int idx = tid * per + i;
            dst[idx] = (unsigned char)(src[idx] != 0 ? 1 : 0);
        }
    } else {
        unsigned* d4 = (unsigned*)dst;
        #pragma unroll
        for (int i = 0; i < 16; i++)
            d4[tid * 16 + i] = src[tid * 16 + i];
    }
    __syncthreads();   // rst8 fully written & drained before Ftab scan

    for (int v = tid; v < NB * (NCH + 1); v += 1024) {
        int n = v / (NCH + 1), c = v - n * (NCH + 1);
        int s = TT;
        const unsigned char* r = dst + n * TT;
        for (int t = c * WCH; t < TT; t++)
            if (r[t]) { s = t; break; }
        Ftab[v] = s;
    }
}

// ---------------------------------------------------------------------------
// Kernel 1: merged weight prep (unchanged from round 4).
// ---------------------------------------------------------------------------
__global__ __launch_bounds__(256) void prep_weights(
    const float* __restrict__ w_i, const float* __restrict__ w_a,
    const float* __restrict__ w_h, const float* __restrict__ ihg,
    float* __restrict__ out3,
    unsigned short* __restrict__ wt, unsigned* __restrict__ whb)
{
    const int bid = blockIdx.x;
    if (bid < 865) {
        int idx = bid * 256 + threadIdx.x;
        const int E2 = GG * KP;          // 221,184
        if (idx < E2) {
            int g = idx / KP, k = idx - g * KP;
            float v = 0.f;
            if (k < FF)            v = w_i[k * GG + g];
            else if (k < FF + AA)  v = w_a[(k - FF) * GG + g];
            wt[idx] = f2h(v);
        } else if (idx < E2 + HH) {
            int i = idx - E2;
            out3[i] = ihg[i];
        }
    } else {
        int j = (bid - 865) * 256 + threadIdx.x;   // dword index, 0..98303
        int w    = j / 12288;
        int r    = j - w * 12288;
        int tile = r >> 8;
        int r2   = r & 255;
        int lane = r2 >> 2, d = r2 & 3;
        int r15 = lane & 15, q = lane >> 4;
        int g, k;
        if (tile < 32) {
            int nt = tile >> 3, kt = tile & 7;
            g = (nt < 2) ? (w * 32 + nt * 16 + r15)
                         : (256 + w * 32 + (nt - 2) * 16 + r15);
            k = kt * 32 + q * 8 + 2 * d;
        } else {
            int t2 = tile - 32;
            int nt2 = t2 >> 3, kt = t2 & 7;
            g = 512 + w * 32 + nt2 * 16 + r15;
            k = kt * 32 + q * 8 + 2 * d;
        }
        whb[j] = pk_rtn(w_h[k * GG + g], w_h[(k + 1) * GG + g]);
    }
}

// ---------------------------------------------------------------------------
// Kernel 2: gxa[MM][GG] (fp16) = [x|a|0] @ W + bias (unchanged from round 4:
// XCD-bijective swizzle + double-buffered LDS, one barrier per kc).
// ---------------------------------------------------------------------------
#define LDK 40

__global__ __launch_bounds__(256, 3) void gemm_fused(
    const float* __restrict__ x, const float* __restrict__ a,
    const unsigned short* __restrict__ wt,
    const float* __restrict__ bias, unsigned short* __restrict__ gxa)
{
    __shared__ __align__(16) unsigned short As[2][128 * LDK];
    __shared__ __align__(16) unsigned short Bs[2][128 * LDK];

    const int bid = blockIdx.x;
    const int wg  = (bid & 7) * 384 + (bid >> 3);   // bijective XCD swizzle
    const int gt = wg % 6, mt = wg / 6;
    const int tid = threadIdx.x;
    const int lane = tid & 63, wv = tid >> 6;
    const int srow = tid & 127, shf = tid >> 7;
    const int r15 = lane & 15, q = lane >> 4;

    v4f acc[2][8];
    #pragma unroll
    for (int i = 0; i < 2; i++)
        #pragma unroll
        for (int j = 0; j < 8; j++) acc[i][j] = (v4f){0.f, 0.f, 0.f, 0.f};

    const int arow = mt * 128 + srow;
    const int brow = gt * 128 + srow;

    float4 f0, f1, f2, f3;
    uint4  pb0, pb1;

    auto issue = [&](int kc) {
        if (kc < 8) {
            const float4* sp = (const float4*)(x + (size_t)arow * FF + kc * 32 + shf * 16);
            f0 = sp[0]; f1 = sp[1]; f2 = sp[2]; f3 = sp[3];
        } else if (shf == 0) {
            const float4* ap = (const float4*)(a + (size_t)arow * AA);
            f0 = ap[0]; f1 = ap[1];
        }
        const uint4* srcB = (const uint4*)(wt + brow * KP + kc * 32 + shf * 16);
        pb0 = srcB[0]; pb1 = srcB[1];
    };
    auto commit = [&](int buf, int kc) {
        uint4 A0, A1;
        if (kc < 8) {
            A0.x = pk_rtn(f0.x, f0.y); A0.y = pk_rtn(f0.z, f0.w);
            A0.z = pk_rtn(f1.x, f1.y); A0.w = pk_rtn(f1.z, f1.w);
            A1.x = pk_rtn(f2.x, f2.y); A1.y = pk_rtn(f2.z, f2.w);
            A1.z = pk_rtn(f3.x, f3.y); A1.w = pk_rtn(f3.z, f3.w);
        } else {
            if (shf == 0) {
                A0.x = pk_rtn(f0.x, f0.y); A0.y = pk_rtn(f0.z, f0.w);
                A0.z = pk_rtn(f1.x, f1.y); A0.w = pk_rtn(f1.z, f1.w);
            } else {
                A0 = (uint4){0, 0, 0, 0};
            }
            A1 = (uint4){0, 0, 0, 0};
        }
        *(uint4*)(As[buf] + srow * LDK + shf * 16)     = A0;
        *(uint4*)(As[buf] + srow * LDK + shf * 16 + 8) = A1;
        *(uint4*)(Bs[buf] + srow * LDK + shf * 16)     = pb0;
        *(uint4*)(Bs[buf] + srow * LDK + shf * 16 + 8) = pb1;
    };

    issue(0);
    commit(0, 0);
    __syncthreads();

    for (int kc = 0; kc < 9; kc++) {
        const int cur = kc & 1;
        if (kc < 8) issue(kc + 1);

        v8h af[2], bf[8];
        #pragma unroll
        for (int mi = 0; mi < 2; mi++)
            af[mi] = *(const v8h*)(As[cur] + (wv * 32 + mi * 16 + r15) * LDK + q * 8);
        #pragma unroll
        for (int nj = 0; nj < 8; nj++)
            bf[nj] = *(const v8h*)(Bs[cur] + (nj * 16 + r15) * LDK + q * 8);
        #pragma unroll
        for (int mi = 0; mi < 2; mi++)
            #pragma unroll
            for (int nj = 0; nj < 8; nj++)
                acc[mi][nj] = __builtin_amdgcn_mfma_f32_16x16x32_f16(
                    af[mi], bf[nj], acc[mi][nj], 0, 0, 0);

        if (kc < 8) {
            commit(cur ^ 1, kc + 1);
            __syncthreads();
        }
    }

    #pragma unroll
    for (int mi = 0; mi < 2; mi++) {
        #pragma unroll
        for (int nj = 0; nj < 8; nj++) {
            int col = gt * 128 + nj * 16 + r15;
            float bv = bias[col];
            #pragma unroll
            for (int v = 0; v < 4; v++) {
                int row = mt * 128 + wv * 32 + mi * 16 + q * 4 + v;
                float val = acc[mi][nj][v] + bv;
                gxa[row * GG + col] = f2h(val);
            }
        }
    }
}

// ---------------------------------------------------------------------------
// Kernel 3: MFMA-batched GRU scan — round-4 structure (single 16-seq unit,
// W=16, 40 reg + 8 LDS weight fragments, LDS-staged gxa double buffer),
// with two changes:
//  (1) in-loop barriers are LDS-only (raw s_barrier + lgkmcnt(0)): the 16
//      output stores and the gxa prefetch loads no longer drain at every
//      __syncthreads (vmcnt(0)) — they stay in flight across barriers.
//  (2) output stores are non-temporal: 128 MB of never-re-read data stops
//      evicting gxa from L3 (keeps scan fetch path L3-resident).
// Math is bit-identical to round 4.
// ---------------------------------------------------------------------------
__global__ __launch_bounds__(512, 2) void scan_mfma(
    const unsigned short* __restrict__ gxa, const uint4* __restrict__ whb4,
    const unsigned char* __restrict__ rst, const int* __restrict__ Ftab,
    const float* __restrict__ ihg, float* __restrict__ out)
{
    __shared__ __align__(16) unsigned short h16[SGRP * LDH];
    __shared__ __align__(16) unsigned short rh16[SGRP * LDH];
    __shared__ __align__(16) unsigned short gstage[2][SGRP * GSP];
    __shared__ __align__(16) uint4 waL[8 * 8 * 64];   // aa1 tiles [w][kt][lane]
    __shared__ int s_tb[SGRP], s_te[SGRP], s_emax;

    const int tid = threadIdx.x;
    const int w = tid >> 6, lane = tid & 63;
    const int r15 = lane & 15, q = lane >> 4;
    const int grp = blockIdx.x >> 6;        // 0..3
    const int c   = blockIdx.x & (NCH - 1); // 0..63
    const int n0  = grp * SGRP;
    const int S   = c * WCH;

    // ---- weights: 40 reg fragments + 8 LDS fragments per wave ----
    uint4 wb[40];
    #pragma unroll
    for (int i = 0; i < 40; i++) wb[i] = whb4[(w * 48 + i) * 64 + lane];
    #pragma unroll
    for (int rr = 0; rr < 8; rr++) {
        int f = rr * 512 + tid;             // [w=rr][kt=tid>>6][lane=tid&63]
        waL[f] = whb4[(rr * 48 + 40 + (tid >> 6)) * 64 + (tid & 63)];
    }

    if (tid < SGRP) {
        s_tb[tid] = (c == 0) ? 0 : Ftab[(n0 + tid) * (NCH + 1) + c];
        s_te[tid] = Ftab[(n0 + tid) * (NCH + 1) + c + 1];
    }
    if (tid == 0) {   // same wave as tid<16 writers: in-wave LDS ordering
        int m = 0;
        for (int i = 0; i < SGRP; i++) m = max(m, s_te[i]);
        s_emax = m;
    }
    // init h16: (c==0 || reset at S) ? ih : 0  (pre-tb values are masked)
    for (int idx = tid; idx < SGRP * HH; idx += 512) {
        int sq = idx >> 8, jj = idx & 255;
        bool rb = (c == 0) || (rst[(n0 + sq) * TT + S] != 0);
        float v = rb ? ihg[jj] : 0.f;
        h16[sq * LDH + jj] = f2h(v);
    }
    // initial gxa stage for t = S
    const int seqS = tid >> 5, jS = tid & 31;
    {
        const uint4* sp = (const uint4*)(gxa + ((size_t)(n0 + seqS) * TT + S) * GG);
        uint4 g0 = sp[jS], g1 = sp[jS + 32], g2 = sp[jS + 64];
        uint4* dp = (uint4*)(gstage[0] + seqS * GSP);
        dp[jS] = g0; dp[jS + 32] = g1; dp[jS + 64] = g2;
    }
    __syncthreads();
    const int Emax = s_emax;

    const int j0 = w * 32 + r15, j1 = j0 + 16;
    const float ih0 = ihg[j0], ih1 = ihg[j1];

    int   seqi[4];    // (n0+seq)*TT row bases for this lane's 4 C-rows
    int   tbte[4];    // tb | te<<16
    float hcr[8];     // fp32 h owned by this lane
    #pragma unroll
    for (int v = 0; v < 4; v++) {
        int sq = q * 4 + v;
        seqi[v] = (n0 + sq) * TT;
        tbte[v] = s_tb[sq] | (s_te[sq] << 16);
        bool rb = (c == 0) || (rst[seqi[v] + S] != 0);
        hcr[v]     = rb ? ih0 : 0.f;
        hcr[4 + v] = rb ? ih1 : 0.f;
    }

    const v4f z4 = {0.f, 0.f, 0.f, 0.f};

    for (int t = S; t < Emax; t++) {
        const int cur = (t - S) & 1, nxt = cur ^ 1;
        const int tn = (t + 1 < TT) ? (t + 1) : (TT - 1);

        // ---- issue next-step global loads (committed at step bottom;
        //      with LDS-only barriers they stay in flight across B1) ----
        uint4 g0, g1, g2;
        {
            const uint4* sp = (const uint4*)(gxa + ((size_t)(n0 + seqS) * TT + tn) * GG);
            g0 = sp[jS]; g1 = sp[jS + 32]; g2 = sp[jS + 64];
        }
        unsigned char rn[4];
        #pragma unroll
        for (int v = 0; v < 4; v++) rn[v] = rst[seqi[v] + tn];

        // ---- phase 1: zr = h @ Wzr  (32 MFMAs/wave) ----
        v4f az0 = z4, az1 = z4, ar0 = z4, ar1 = z4;
        #pragma unroll
        for (int kt = 0; kt < 8; kt++) {
            v8h af = *(const v8h*)(h16 + r15 * LDH + kt * 32 + q * 8);
            az0 = __builtin_amdgcn_mfma_f32_16x16x32_f16(af, __builtin_bit_cast(v8h, wb[kt]),      az0, 0, 0, 0);
            az1 = __builtin_amdgcn_mfma_f32_16x16x32_f16(af, __builtin_bit_cast(v8h, wb[8 + kt]),  az1, 0, 0, 0);
            ar0 = __builtin_amdgcn_mfma_f32_16x16x32_f16(af, __builtin_bit_cast(v8h, wb[16 + kt]), ar0, 0, 0, 0);
            ar1 = __builtin_amdgcn_mfma_f32_16x16x32_f16(af, __builtin_bit_cast(v8h, wb[24 + kt]), ar1, 0, 0, 0);
        }

        // ---- epilogue 1: sigmoid; z kept local; rh -> LDS (fp16) ----
        const unsigned short* gs = gstage[cur];
        float zs[8];
        #pragma unroll
        for (int v = 0; v < 4; v++) {
            int sq = q * 4 + v;
            int gb = sq * GSP;
            float z0 = az0[v] + h2f(gs[gb + j0]);
            float z1 = az1[v] + h2f(gs[gb + j1]);
            zs[v]     = 1.f / (1.f + __expf(-z0));
            zs[4 + v] = 1.f / (1.f + __expf(-z1));
            float r0 = ar0[v] + h2f(gs[gb + 256 + j0]);
            float r1 = ar1[v] + h2f(gs[gb + 256 + j1]);
            float s0 = 1.f / (1.f + __expf(-r0));
            float s1 = 1.f / (1.f + __expf(-r1));
            rh16[sq * LDH + j0] = f2h(s0 * hcr[v]);
            rh16[sq * LDH + j1] = f2h(s1 * hcr[4 + v]);
        }
        bar_lds();   // B1: rh16 ready (prefetch loads NOT drained here)

        // ---- phase 2: a = rh @ Wa  (16 MFMAs/wave, 8 B-frags from LDS) ----
        v4f aa0 = z4, aa1 = z4;
        #pragma unroll
        for (int kt = 0; kt < 8; kt++) {
            v8h af = *(const v8h*)(rh16 + r15 * LDH + kt * 32 + q * 8);
            uint4 wv4 = waL[(w * 8 + kt) * 64 + lane];
            aa0 = __builtin_amdgcn_mfma_f32_16x16x32_f16(af, __builtin_bit_cast(v8h, wb[32 + kt]), aa0, 0, 0, 0);
            aa1 = __builtin_amdgcn_mfma_f32_16x16x32_f16(af, __builtin_bit_cast(v8h, wv4),         aa1, 0, 0, 0);
        }

        // ---- epilogue 2: tanh, state update, masked NT store, next reset ----
        #pragma unroll
        for (int v = 0; v < 4; v++) {
            int sq = q * 4 + v;
            int gb = sq * GSP;
            int tb = tbte[v] & 0xFFFF, te = tbte[v] >> 16;
            bool wr = (t >= tb) && (t < te);
            int mo = (seqi[v] + t) * HH;
            float u0 = aa0[v] + h2f(gs[gb + 512 + j0]);
            float u1 = aa1[v] + h2f(gs[gb + 512 + j1]);
            float e0 = __expf(2.f * u0), e1 = __expf(2.f * u1);
            float t0 = (e0 - 1.f) / (e0 + 1.f);
            float t1 = (e1 - 1.f) / (e1 + 1.f);
            float hn0 = hcr[v]     + zs[v]     * (t0 - hcr[v]);
            float hn1 = hcr[4 + v] + zs[4 + v] * (t1 - hcr[4 + v]);
            if (wr) {
                __builtin_nontemporal_store(hn0, out + mo + j0);
                __builtin_nontemporal_store(hn1, out + mo + j1);
                __builtin_nontemporal_store(hn0, out + MM * HH + mo + j0);
                __builtin_nontemporal_store(hn1, out + MM * HH + mo + j1);
            }
            bool rb = rn[v] != 0;
            float g0f = rb ? ih0 : hn0;
            float g1f = rb ? ih1 : hn1;
            hcr[v] = g0f; hcr[4 + v] = g1f;
            h16[sq * LDH + j0] = f2h(g0f);
            h16[sq * LDH + j1] = f2h(g1f);
        }

        // ---- commit staged gxa for t+1 (vmcnt counted wait on g0..g2 only) ----
        {
            uint4* dp = (uint4*)(gstage[nxt] + seqS * GSP);
            dp[jS] = g0; dp[jS + 32] = g1; dp[jS + 64] = g2;
        }
        bar_lds();   // B2: h16 + gstage[nxt] ready (stores NOT drained)
    }
}

// ---------------------------------------------------------------------------
extern "C" void kernel_launch(void* const* d_in, const int* in_sizes, int n_in,
                              void* d_out, int out_size, void* d_ws, size_t ws_size,
                              hipStream_t stream)
{
    const float* x   = (const float*)d_in[0];
    const float* a   = (const float*)d_in[1];
    const void*  rsv = d_in[2];
    const float* w_i = (const float*)d_in[3];
    const float* w_h = (const float*)d_in[4];
    const float* w_a = (const float*)d_in[5];
    const float* b   = (const float*)d_in[6];
    const float* ih  = (const float*)d_in[7];
    float*       out = (float*)d_out;

    char* ws = (char*)d_ws;
    size_t o = 0;
    unsigned short* gxa  = (unsigned short*)(ws + o); o += (size_t)MM * GG * 2;  // 96 MB
    unsigned short* wt   = (unsigned short*)(ws + o); o += (size_t)GG * KP * 2;  // 0.44 MB
    unsigned char*  rst8 = (unsigned char*) (ws + o); o += (size_t)NB * TT;      // 64 KB
    unsigned*       whb  = (unsigned*)      (ws + o); o += 98304u * 4;           // 384 KB
    int*            Ftab = (int*)           (ws + o);                            // 64*65 ints

    fix_reset<<<1, 1024, 0, stream>>>((const unsigned*)rsv, rst8, Ftab);

    prep_weights<<<865 + 384, 256, 0, stream>>>(
        w_i, w_a, w_h, ih, out + (size_t)2 * MM * HH, wt, whb);

    gemm_fused<<<512 * 6, 256, 0, stream>>>(x, a, wt, b, gxa);

    scan_mfma<<<(NB / SGRP) * NCH, 512, 0, stream>>>(
        gxa, (const uint4*)whb, rst8, Ftab, ih, out);
}